// Round 6
// baseline (53.025 us; speedup 1.0000x reference)
//
#include <hip/hip_runtime.h>
#include <hip/hip_bf16.h>

#define CIN_ 16
#define COUT_ 32
#define NBATCH_ 16
#define H_ 64
#define W_ 64
#define F_ 10                   // silu + 8 bases + zero pad -> K=160 per tap = 10 x 16
#define LPIX_ 336               // LDS bytes per pixel (320 data + 16 pad)
#define PXT_ 34                 // staged pixels per row (32 out + 2 halo)
#define LROWT_ (PXT_ * LPIX_)   // 11424 B per staged input row
#define ROWS_ 6                 // staged input rows (4 output rows + 2 halo)
#define NSITE_ (ROWS_ * PXT_)   // 204 (row,px) sites per ci
#define NIT_ 13                 // ceil(204/16) prefetch iterations
#define NPACK_ 18               // packer blocks
#define NTILE_ 512              // consumer tiles (= grid size)
#define MAGIC_ 0x5EEDF00Du
#define WPKSH_ (9 * 10 * 64 * 8)   // 46080 ushorts = 92160 B

typedef __attribute__((ext_vector_type(8))) short short8;
typedef __attribute__((ext_vector_type(4))) float f32x4;
typedef __attribute__((ext_vector_type(16))) float f32x16;

__device__ __forceinline__ unsigned short f2bf(float f) {
    unsigned u = __builtin_bit_cast(unsigned, f);
    u += 0x7FFFu + ((u >> 16) & 1u);
    return (unsigned short)(u >> 16);
}
__device__ __forceinline__ unsigned pack2(float lo, float hi) {
    return (unsigned)f2bf(lo) | ((unsigned)f2bf(hi) << 16);
}

// Single-dispatch fused kernel.
// Blocks 0..17: pack weights -> wpk, release flag, then work tile 494+pid.
// Blocks 18..511: work tile pid-18 (phase 1 overlaps packing; GEMM gated on flags).
__global__ __launch_bounds__(256, 2) void kan_one(const float* __restrict__ x,
                                                  const float* __restrict__ bw,
                                                  const float* __restrict__ sw,
                                                  const float* __restrict__ sc,
                                                  unsigned short* __restrict__ wpk,
                                                  unsigned* __restrict__ flags,
                                                  float* __restrict__ out) {
    __shared__ __align__(16) char lA[ROWS_ * LROWT_];   // 68,544 B
    int tid = threadIdx.x;
    int pid = blockIdx.x;

    // ---- Producer role: pack weights into per-lane 32x32x16 B-fragment order.
    // wpk layout [tap(9)][step(10)][lane(64)][8 bf16]; k = ci*10+f;
    // per-lane k = step*16 + (lane>>5)*8 + j, n = lane&31. Every byte written.
    if (pid < NPACK_) {
        int e = pid * 256 + tid;   // e = (n*16+ci)*10... actually (n*CIN_+ci)*9+tap
        if (e < 32 * 16 * 9) {
            int n = e / 144;
            int ci = (e / 9) & 15;
            int tap = e % 9;
            float bwv = bw[e];
            float scv = sc[e];
            float4 s0 = *(const float4*)(sw + (size_t)e * 8);
            float4 s1 = *(const float4*)(sw + (size_t)e * 8 + 4);
            float swv[8] = {s0.x, s0.y, s0.z, s0.w, s1.x, s1.y, s1.z, s1.w};
#pragma unroll
            for (int f = 0; f < 10; ++f) {
                float v = (f == 0) ? bwv : (f <= 8 ? swv[f - 1] * scv : 0.0f);
                int k = ci * 10 + f;
                int step = k >> 4, r = k & 15;
                int lane = ((r >> 3) << 5) | n;
                int j = r & 7;
                wpk[((size_t)(tap * 10 + step) * 64 + lane) * 8 + j] = f2bf(v);
            }
        }
        __threadfence();          // make this thread's wpk stores device-visible
        __syncthreads();          // whole block done
        if (tid == 0)
            __hip_atomic_store(&flags[pid], MAGIC_, __ATOMIC_RELEASE,
                               __HIP_MEMORY_SCOPE_AGENT);
    }

    // ---- Consumer role: tile = (batch, 4-row group, 32-px half) ----
    int tile = (pid < NPACK_) ? (NTILE_ - NPACK_ + pid) : (pid - NPACK_);
    int bb = tile >> 5;
    int rem = tile & 31;
    int h0 = (rem >> 1) * 4;
    int w0 = (rem & 1) * 32;

    // Phase 1: features into LDS; x-loads register-prefetched (batched latency).
    {
        int ci = tid >> 4;
        int l = tid & 15;
        const float* xb = x + ((size_t)bb * CIN_ + ci) * (H_ * W_);
        float xr[NIT_];
#pragma unroll
        for (int it = 0; it < NIT_; ++it) {
            int s = it * 16 + l;
            int r = s / PXT_;
            int lpx = s - r * PXT_;
            int hy = h0 + r - 1;
            int wx = w0 + lpx - 1;
            bool v = (s < NSITE_) && (hy >= 0) && (hy < H_) && (wx >= 0) && (wx < W_);
            xr[it] = v ? xb[hy * W_ + wx] : 0.f;
        }
#pragma unroll
        for (int it = 0; it < NIT_; ++it) {
            int s = it * 16 + l;
            if (s < NSITE_) {
                int r = s / PXT_;
                int lpx = s - r * PXT_;
                float xv = xr[it];
                // closed-form uniform cubic B-spline, knots t_j = 0.4j-2.2
                float ua = (xv + 2.2f) * 2.5f;
                float mf = floorf(ua);
                float u = ua - mf;
                bool ok = (ua >= 0.0f) && (ua < 11.0f);
                float u2 = u * u, u3 = u2 * u;
                const float c6 = 1.0f / 6.0f;
                float Bm  = u3 * c6;
                float Bm1 = (-3.f * u3 + 3.f * u2 + 3.f * u + 1.f) * c6;
                float Bm2 = (3.f * u3 - 6.f * u2 + 4.f) * c6;
                float om = 1.f - u;
                float Bm3 = om * om * om * c6;
                // window placement: shorts (m-2..m+1) = [Bm3,Bm2,Bm1,Bm];
                // short 0 is overwritten by silu; shorts >=10 dropped (q<5);
                // short 9 is the zero-weight pad (weight 0 in wpk).
                unsigned P0 = pack2(Bm3, Bm2);
                unsigned P1 = pack2(Bm1, Bm);
                int sh = ok ? ((int)mf - 2) : 99;
                int a = sh >> 1;
                bool odd = sh & 1;
                unsigned Q0 = odd ? (P0 << 16) : P0;
                unsigned Q1 = odd ? ((P0 >> 16) | (P1 << 16)) : P1;
                unsigned Q2 = odd ? (P1 >> 16) : 0u;
                unsigned wq[5];
#pragma unroll
                for (int q = 0; q < 5; ++q)
                    wq[q] = (q == a) ? Q0 : (q == a + 1) ? Q1 : (q == a + 2) ? Q2 : 0u;
                float sil = xv * __builtin_amdgcn_rcpf(1.f + __expf(-xv));
                wq[0] = (wq[0] & 0xFFFF0000u) | (unsigned)f2bf(sil);
                unsigned* dst = (unsigned*)(lA + r * LROWT_ + lpx * LPIX_ + ci * 20);
#pragma unroll
                for (int q = 0; q < 5; ++q) dst[q] = wq[q];
            }
        }
    }

    // Gate on packed weights: wave 0 spins (acquire, agent scope).
    if (tid < 64) {
        for (;;) {
            unsigned v = (tid < NPACK_)
                ? __hip_atomic_load(&flags[tid], __ATOMIC_ACQUIRE, __HIP_MEMORY_SCOPE_AGENT)
                : MAGIC_;
            if (__all(v == MAGIC_)) break;
            __builtin_amdgcn_s_sleep(4);
        }
    }
    __syncthreads();      // phase-1 LDS ready + flags observed by wave 0
    __threadfence();      // acquire fence for all threads before wpk reads

    int lane = tid & 63, wv = tid >> 6;

    // B fragments (10 per tap) double-buffered in registers.
    short8 B[2][10];
#pragma unroll
    for (int s = 0; s < 10; ++s)
        B[0][s] = *(const short8*)(wpk + ((size_t)s * 64 + lane) * 8);

    // Phase 2: 90 x mfma_f32_32x32x16_bf16 per wave (1 row x 32 px x 32 ch).
    f32x16 acc = {};
#pragma unroll
    for (int tap = 0; tap < 9; ++tap) {
        int cur = tap & 1, nxt = cur ^ 1;
        if (tap < 8) {
#pragma unroll
            for (int s = 0; s < 10; ++s)
                B[nxt][s] = *(const short8*)(wpk +
                    ((size_t)((tap + 1) * 10 + s) * 64 + lane) * 8);
        }
        int ki = tap / 3, kj = tap - ki * 3;
        const char* abase = lA + (wv + ki) * LROWT_ + ((lane & 31) + kj) * LPIX_ +
                            ((lane >> 5) << 4);
        __builtin_amdgcn_s_setprio(1);
#pragma unroll
        for (int s = 0; s < 10; ++s) {
            short8 av = *(const short8*)(abase + s * 32);
            acc = __builtin_amdgcn_mfma_f32_32x32x16_bf16(av, B[cur][s], acc, 0, 0, 0);
        }
        __builtin_amdgcn_s_setprio(0);
    }

    // Epilogue: C/D 32x32 layout: n(ch) = lane&31,
    // m(px) = (reg&3) + 8*(reg>>2) + 4*(lane>>5)  [HW-verified]
    int ch = lane & 31;
    int hh = h0 + wv;
    float* ob = out + (size_t)bb * COUT_ * (H_ * W_) + (size_t)ch * (H_ * W_) +
                (size_t)hh * W_ + w0;
#pragma unroll
    for (int q = 0; q < 4; ++q) {
        int px0 = q * 8 + ((lane >> 5) << 2);
        f32x4 v = {acc[q * 4 + 0], acc[q * 4 + 1], acc[q * 4 + 2], acc[q * 4 + 3]};
        __builtin_nontemporal_store(v, (f32x4*)(ob + px0));
    }
}

// Fallback (only if workspace is too small): direct fp32 compute, slow but correct.
__device__ __forceinline__ void kan_feat_ref(float xv, float* f) {
    float ua = (xv + 2.2f) * 2.5f;
    float mf = floorf(ua);
    int m = (int)mf;
    float u = ua - mf;
    bool ok = (ua >= 0.0f) && (ua < 11.0f);
    float u2 = u * u, u3 = u2 * u;
    const float c6 = 1.0f / 6.0f;
    float Bm  = u3 * c6;
    float Bm1 = (-3.f * u3 + 3.f * u2 + 3.f * u + 1.f) * c6;
    float Bm2 = (3.f * u3 - 6.f * u2 + 4.f) * c6;
    float om = 1.f - u;
    float Bm3 = om * om * om * c6;
    if (!ok) { Bm = 0.f; Bm1 = 0.f; Bm2 = 0.f; Bm3 = 0.f; }
    f[0] = xv / (1.f + __expf(-xv));
#pragma unroll
    for (int j = 0; j < 8; ++j) {
        float v = 0.f;
        v = (m == j)     ? Bm  : v;
        v = (m == j + 1) ? Bm1 : v;
        v = (m == j + 2) ? Bm2 : v;
        v = (m == j + 3) ? Bm3 : v;
        f[1 + j] = v;
    }
}

__global__ void kan_direct(const float* __restrict__ x, const float* __restrict__ bw,
                           const float* __restrict__ sw, const float* __restrict__ sc,
                           float* __restrict__ out) {
    int idx = blockIdx.x * 256 + threadIdx.x;
    if (idx >= NBATCH_ * COUT_ * H_ * W_) return;
    int w = idx & 63, hh = (idx >> 6) & 63, o = (idx >> 12) & 31, b = idx >> 17;
    float acc = 0.0f;
    for (int i = 0; i < CIN_; ++i)
        for (int ki = 0; ki < 3; ++ki)
            for (int kj = 0; kj < 3; ++kj) {
                int hy = hh + ki - 1, wx = w + kj - 1;
                float xv = (hy >= 0 && hy < H_ && wx >= 0 && wx < W_)
                               ? x[(((size_t)b * CIN_ + i) * H_ + hy) * W_ + wx]
                               : 0.0f;
                float f[9];
                kan_feat_ref(xv, f);
                int idx9 = (o * CIN_ + i) * 9 + ki * 3 + kj;
                float a = f[0] * bw[idx9];
                float s = sc[idx9];
#pragma unroll
                for (int cc = 0; cc < 8; ++cc) a += f[1 + cc] * sw[idx9 * 8 + cc] * s;
                acc += a;
            }
    out[idx] = acc;
}

extern "C" void kernel_launch(void* const* d_in, const int* in_sizes, int n_in,
                              void* d_out, int out_size, void* d_ws, size_t ws_size,
                              hipStream_t stream) {
    const float* x  = (const float*)d_in[0];
    const float* bw = (const float*)d_in[1];
    const float* sw = (const float*)d_in[2];
    const float* sc = (const float*)d_in[3];
    float* out = (float*)d_out;

    size_t need = (size_t)WPKSH_ * 2 + NPACK_ * sizeof(unsigned);   // 92,232 B
    if (ws_size >= need) {
        unsigned short* wpk = (unsigned short*)d_ws;
        unsigned* flags = (unsigned*)((char*)d_ws + (size_t)WPKSH_ * 2);
        kan_one<<<dim3(NTILE_), 256, 0, stream>>>(x, bw, sw, sc, wpk, flags, out);
    } else {
        kan_direct<<<dim3((NBATCH_ * COUT_ * H_ * W_ + 255) / 256), 256, 0, stream>>>(
            x, bw, sw, sc, out);
    }
}

// Round 7
// 28.680 us; speedup vs baseline: 1.8488x; 1.8488x over previous
//
#include <hip/hip_runtime.h>
#include <hip/hip_bf16.h>

#define CIN_ 16
#define COUT_ 32
#define NBATCH_ 16
#define H_ 64
#define W_ 64
#define F_ 10                   // silu + 8 bases + zero pad -> K=160 per tap
#define LPIX_ 336               // LDS bytes per pixel (320 data + 16 pad)
#define PXT_ 18                 // staged pixels per row (16 out + 2 halo)
#define LROWT_ (PXT_ * LPIX_)   // 6048 B per staged input row
#define ROWS_ 6                 // staged input rows (4 output rows + 2 halo)
#define NSITE_ (ROWS_ * PXT_)   // 108 (row,px) sites per ci
#define NIT_ 7                  // ceil(108/16) prefetch iterations

typedef __attribute__((ext_vector_type(8))) short short8;
typedef __attribute__((ext_vector_type(4))) float f32x4;

__device__ __forceinline__ unsigned short f2bf(float f) {
    unsigned u = __builtin_bit_cast(unsigned, f);
    u += 0x7FFFu + ((u >> 16) & 1u);
    return (unsigned short)(u >> 16);
}
__device__ __forceinline__ unsigned pack2(float lo, float hi) {
    return (unsigned)f2bf(lo) | ((unsigned)f2bf(hi) << 16);
}

// Pack weights into per-lane MFMA B-fragment order (16x16x32):
// layout [tap(9)][nt(2)][c(5)][lane(64)][8 bf16]; k = ci*10 + f;
// per-lane k = c*32 + (lane>>4)*8 + j, n = nt*16 + (lane&15).
// Thread owns (n,ci,tap): contiguous sw loads, 10 scattered u16 stores.
// Every wpk byte written exactly once (poison-safe).
__global__ void kan_packw(const float* __restrict__ bw, const float* __restrict__ sw,
                          const float* __restrict__ sc, unsigned short* __restrict__ wpk) {
    int e = blockIdx.x * 256 + threadIdx.x;   // e = (n*CIN_+ci)*9+tap
    if (e >= 32 * 16 * 9) return;
    int n = e / 144;
    int ci = (e / 9) & 15;
    int tap = e % 9;
    float bwv = bw[e];
    float scv = sc[e];
    float4 s0 = *(const float4*)(sw + (size_t)e * 8);
    float4 s1 = *(const float4*)(sw + (size_t)e * 8 + 4);
    float swv[8] = {s0.x, s0.y, s0.z, s0.w, s1.x, s1.y, s1.z, s1.w};
    int nt = n >> 4, nl = n & 15;
#pragma unroll
    for (int f = 0; f < 10; ++f) {
        float v = (f == 0) ? bwv : (f <= 8 ? swv[f - 1] * scv : 0.0f);
        int k = ci * 10 + f;
        int c = k >> 5, r = k & 31;
        int lane = ((r >> 3) << 4) | nl;
        int j = r & 7;
        wpk[((size_t)(((tap * 2 + nt) * 5 + c)) * 64 + lane) * 8 + j] = f2bf(v);
    }
}

// Fused featurize + implicit-GEMM conv, 16x16x32 MFMA.
// Block = (batch, 4 output rows, 16-px quarter); wave wv = output row h0+wv,
// 16 px x 32 ch (M1xN2). LDS 36.3 KB -> 4 blocks/CU = 4 waves/SIMD.
__global__ __launch_bounds__(256, 4) void kan_fused(const float* __restrict__ x,
                                                    const unsigned short* __restrict__ wpk,
                                                    float* __restrict__ out) {
    __shared__ __align__(16) char lA[ROWS_ * LROWT_];   // 36,288 B
    int tid = threadIdx.x;
    int bb = blockIdx.x >> 6;
    int rem = blockIdx.x & 63;
    int h0 = (rem >> 2) * 4;
    int w0 = (rem & 3) * 16;

    // ---- Phase 1: features into LDS; x-loads register-prefetched ----
    {
        int ci = tid >> 4;
        int l = tid & 15;
        const float* xb = x + ((size_t)bb * CIN_ + ci) * (H_ * W_);
        float xr[NIT_];
#pragma unroll
        for (int it = 0; it < NIT_; ++it) {
            int s = it * 16 + l;
            int r = s / PXT_;
            int lpx = s - r * PXT_;
            int hy = h0 + r - 1;
            int wx = w0 + lpx - 1;
            bool v = (s < NSITE_) && (hy >= 0) && (hy < H_) && (wx >= 0) && (wx < W_);
            xr[it] = v ? xb[hy * W_ + wx] : 0.f;   // all loads in flight together
        }
#pragma unroll
        for (int it = 0; it < NIT_; ++it) {
            int s = it * 16 + l;
            if (s < NSITE_) {
                int r = s / PXT_;
                int lpx = s - r * PXT_;
                float xv = xr[it];
                // closed-form uniform cubic B-spline, knots t_j = 0.4j-2.2
                float ua = (xv + 2.2f) * 2.5f;
                float mf = floorf(ua);
                float u = ua - mf;
                bool ok = (ua >= 0.0f) && (ua < 11.0f);
                float u2 = u * u, u3 = u2 * u;
                const float c6 = 1.0f / 6.0f;
                float Bm  = u3 * c6;
                float Bm1 = (-3.f * u3 + 3.f * u2 + 3.f * u + 1.f) * c6;
                float Bm2 = (3.f * u3 - 6.f * u2 + 4.f) * c6;
                float om = 1.f - u;
                float Bm3 = om * om * om * c6;
                // window placement: shorts (m-2..m+1) = [Bm3,Bm2,Bm1,Bm];
                // short 0 overwritten by silu; shorts >=10 dropped (q<5);
                // short 9 is the zero-weight pad.
                unsigned P0 = pack2(Bm3, Bm2);
                unsigned P1 = pack2(Bm1, Bm);
                int sh = ok ? ((int)mf - 2) : 99;
                int a = sh >> 1;
                bool odd = sh & 1;
                unsigned Q0 = odd ? (P0 << 16) : P0;
                unsigned Q1 = odd ? ((P0 >> 16) | (P1 << 16)) : P1;
                unsigned Q2 = odd ? (P1 >> 16) : 0u;
                unsigned wq[5];
#pragma unroll
                for (int q = 0; q < 5; ++q)
                    wq[q] = (q == a) ? Q0 : (q == a + 1) ? Q1 : (q == a + 2) ? Q2 : 0u;
                float sil = xv * __builtin_amdgcn_rcpf(1.f + __expf(-xv));
                wq[0] = (wq[0] & 0xFFFF0000u) | (unsigned)f2bf(sil);
                unsigned* dst = (unsigned*)(lA + r * LROWT_ + lpx * LPIX_ + ci * 20);
#pragma unroll
                for (int q = 0; q < 5; ++q) dst[q] = wq[q];
            }
        }
    }
    __syncthreads();

    int lane = tid & 63, wv = tid >> 6;
    int lrow = lane & 15, khalf = lane >> 4;

    // ---- Phase 2: wave owns row h0+wv, 16 px x 32 ch. Single-buffered B
    // (40 VGPR) -- latency hidden by 4 waves/SIMD occupancy.
    f32x4 acc[2] = {{0.f, 0.f, 0.f, 0.f}, {0.f, 0.f, 0.f, 0.f}};

#pragma unroll
    for (int tap = 0; tap < 9; ++tap) {
        short8 B[5][2];
#pragma unroll
        for (int c = 0; c < 5; ++c)
#pragma unroll
            for (int nt = 0; nt < 2; ++nt)
                B[c][nt] = *(const short8*)(wpk +
                    ((size_t)(((tap * 2 + nt) * 5 + c)) * 64 + lane) * 8);
        int ki = tap / 3, kj = tap - ki * 3;
        const char* abase = lA + (wv + ki) * LROWT_ + (lrow + kj) * LPIX_ + khalf * 16;
        __builtin_amdgcn_s_setprio(1);
#pragma unroll
        for (int c = 0; c < 5; ++c) {
            short8 av = *(const short8*)(abase + c * 64);
            acc[0] = __builtin_amdgcn_mfma_f32_16x16x32_bf16(av, B[c][0], acc[0], 0, 0, 0);
            acc[1] = __builtin_amdgcn_mfma_f32_16x16x32_bf16(av, B[c][1], acc[1], 0, 0, 0);
        }
        __builtin_amdgcn_s_setprio(0);
    }

    // ---- Epilogue: C layout (16x16): ch = nt*16 + (lane&15), px = khalf*4+reg.
    // Lanes {g,g+16,g+32,g+48} cover one 64B line per channel.
    int hh = h0 + wv;
    float* ob = out + (size_t)bb * COUT_ * (H_ * W_) + (size_t)hh * W_ + w0;
#pragma unroll
    for (int nt = 0; nt < 2; ++nt) {
        int och = nt * 16 + lrow;
        f32x4 v = acc[nt];
        __builtin_nontemporal_store(v,
            (f32x4*)(ob + (size_t)och * (H_ * W_) + khalf * 4));
    }
}

// Fallback (only if workspace is too small): direct fp32 compute, slow but correct.
__device__ __forceinline__ void kan_feat_ref(float xv, float* f) {
    float ua = (xv + 2.2f) * 2.5f;
    float mf = floorf(ua);
    int m = (int)mf;
    float u = ua - mf;
    bool ok = (ua >= 0.0f) && (ua < 11.0f);
    float u2 = u * u, u3 = u2 * u;
    const float c6 = 1.0f / 6.0f;
    float Bm  = u3 * c6;
    float Bm1 = (-3.f * u3 + 3.f * u2 + 3.f * u + 1.f) * c6;
    float Bm2 = (3.f * u3 - 6.f * u2 + 4.f) * c6;
    float om = 1.f - u;
    float Bm3 = om * om * om * c6;
    if (!ok) { Bm = 0.f; Bm1 = 0.f; Bm2 = 0.f; Bm3 = 0.f; }
    f[0] = xv / (1.f + __expf(-xv));
#pragma unroll
    for (int j = 0; j < 8; ++j) {
        float v = 0.f;
        v = (m == j)     ? Bm  : v;
        v = (m == j + 1) ? Bm1 : v;
        v = (m == j + 2) ? Bm2 : v;
        v = (m == j + 3) ? Bm3 : v;
        f[1 + j] = v;
    }
}

__global__ void kan_direct(const float* __restrict__ x, const float* __restrict__ bw,
                           const float* __restrict__ sw, const float* __restrict__ sc,
                           float* __restrict__ out) {
    int idx = blockIdx.x * 256 + threadIdx.x;
    if (idx >= NBATCH_ * COUT_ * H_ * W_) return;
    int w = idx & 63, hh = (idx >> 6) & 63, o = (idx >> 12) & 31, b = idx >> 17;
    float acc = 0.0f;
    for (int i = 0; i < CIN_; ++i)
        for (int ki = 0; ki < 3; ++ki)
            for (int kj = 0; kj < 3; ++kj) {
                int hy = hh + ki - 1, wx = w + kj - 1;
                float xv = (hy >= 0 && hy < H_ && wx >= 0 && wx < W_)
                               ? x[(((size_t)b * CIN_ + i) * H_ + hy) * W_ + wx]
                               : 0.0f;
                float f[9];
                kan_feat_ref(xv, f);
                int idx9 = (o * CIN_ + i) * 9 + ki * 3 + kj;
                float a = f[0] * bw[idx9];
                float s = sc[idx9];
#pragma unroll
                for (int cc = 0; cc < 8; ++cc) a += f[1 + cc] * sw[idx9 * 8 + cc] * s;
                acc += a;
            }
    out[idx] = acc;
}

extern "C" void kernel_launch(void* const* d_in, const int* in_sizes, int n_in,
                              void* d_out, int out_size, void* d_ws, size_t ws_size,
                              hipStream_t stream) {
    const float* x  = (const float*)d_in[0];
    const float* bw = (const float*)d_in[1];
    const float* sw = (const float*)d_in[2];
    const float* sc = (const float*)d_in[3];
    float* out = (float*)d_out;

    size_t need = (size_t)9 * 2 * 5 * 64 * 8 * 2;   // 92,160 B packed weights
    if (ws_size >= need) {
        unsigned short* wpk = (unsigned short*)d_ws;
        kan_packw<<<dim3(18), 256, 0, stream>>>(bw, sw, sc, wpk);
        kan_fused<<<dim3(NBATCH_ * 64), 256, 0, stream>>>(x, wpk, out);
    } else {
        kan_direct<<<dim3((NBATCH_ * COUT_ * H_ * W_ + 255) / 256), 256, 0, stream>>>(
            x, bw, sw, sc, out);
    }
}

// Round 8
// 20.384 us; speedup vs baseline: 2.6012x; 1.4070x over previous
//
#include <hip/hip_runtime.h>
#include <hip/hip_bf16.h>

#define CIN_ 16
#define COUT_ 32
#define NBATCH_ 16
#define H_ 64
#define W_ 64
#define F_ 10                   // silu + 8 bases + zero pad -> K=160 per tap
#define LPIX_ 336               // LDS bytes per pixel (320 data + 16 pad)
#define PXT_ 18                 // staged pixels per row (16 out + 2 halo)
#define LROWT_ (PXT_ * LPIX_)   // 6048 B per staged input row
#define ROWS_ 6                 // staged input rows (4 output rows + 2 halo)
#define NSITE_ (ROWS_ * PXT_)   // 108 (row,px) sites per ci
#define NIT_ 7                  // ceil(108/16) prefetch iterations

typedef __attribute__((ext_vector_type(8))) short short8;
typedef __attribute__((ext_vector_type(4))) float f32x4;

__device__ __forceinline__ unsigned short f2bf(float f) {
    unsigned u = __builtin_bit_cast(unsigned, f);
    u += 0x7FFFu + ((u >> 16) & 1u);
    return (unsigned short)(u >> 16);
}
__device__ __forceinline__ unsigned pack2(float lo, float hi) {
    return (unsigned)f2bf(lo) | ((unsigned)f2bf(hi) << 16);
}

// Pack weights into per-lane MFMA B-fragment order (16x16x32):
// layout [tap(9)][nt(2)][c(5)][lane(64)][8 bf16]; k = ci*10 + f;
// per-lane k = c*32 + (lane>>4)*8 + j, n = nt*16 + (lane&15).
// Thread owns (n,ci,tap): contiguous sw loads, 10 scattered u16 stores.
// Every wpk byte written exactly once (poison-safe).
__global__ void kan_packw(const float* __restrict__ bw, const float* __restrict__ sw,
                          const float* __restrict__ sc, unsigned short* __restrict__ wpk) {
    int e = blockIdx.x * 256 + threadIdx.x;   // e = (n*CIN_+ci)*9+tap
    if (e >= 32 * 16 * 9) return;
    int n = e / 144;
    int ci = (e / 9) & 15;
    int tap = e % 9;
    float bwv = bw[e];
    float scv = sc[e];
    float4 s0 = *(const float4*)(sw + (size_t)e * 8);
    float4 s1 = *(const float4*)(sw + (size_t)e * 8 + 4);
    float swv[8] = {s0.x, s0.y, s0.z, s0.w, s1.x, s1.y, s1.z, s1.w};
    int nt = n >> 4, nl = n & 15;
#pragma unroll
    for (int f = 0; f < 10; ++f) {
        float v = (f == 0) ? bwv : (f <= 8 ? swv[f - 1] * scv : 0.0f);
        int k = ci * 10 + f;
        int c = k >> 5, r = k & 31;
        int lane = ((r >> 3) << 4) | nl;
        int j = r & 7;
        wpk[((size_t)(((tap * 2 + nt) * 5 + c)) * 64 + lane) * 8 + j] = f2bf(v);
    }
}

// Fused featurize + implicit-GEMM conv, 16x16x32 MFMA.
// Block = (batch, 4 output rows, 16-px quarter). 36.3 KB LDS -> 4 blocks/CU
// = 4 waves/SIMD. Wave wv -> (row-pair p = wv&1, channel-half nt = wv>>1):
// 2 rows x 16 px x 16 ch (M2xN1), B double-buffered (R4 wave economics at 2x
// occupancy -- the clean occupancy A/B vs R4).
__global__ __launch_bounds__(256, 4) void kan_fused(const float* __restrict__ x,
                                                    const unsigned short* __restrict__ wpk,
                                                    float* __restrict__ out) {
    __shared__ __align__(16) char lA[ROWS_ * LROWT_];   // 36,288 B
    int tid = threadIdx.x;
    int bb = blockIdx.x >> 6;
    int rem = blockIdx.x & 63;
    int h0 = (rem >> 2) * 4;
    int w0 = (rem & 3) * 16;

    // ---- Phase 1: features into LDS; x-loads register-prefetched ----
    {
        int ci = tid >> 4;
        int l = tid & 15;
        const float* xb = x + ((size_t)bb * CIN_ + ci) * (H_ * W_);
        float xr[NIT_];
#pragma unroll
        for (int it = 0; it < NIT_; ++it) {
            int s = it * 16 + l;
            int r = s / PXT_;
            int lpx = s - r * PXT_;
            int hy = h0 + r - 1;
            int wx = w0 + lpx - 1;
            bool v = (s < NSITE_) && (hy >= 0) && (hy < H_) && (wx >= 0) && (wx < W_);
            xr[it] = v ? xb[hy * W_ + wx] : 0.f;   // all loads in flight together
        }
#pragma unroll
        for (int it = 0; it < NIT_; ++it) {
            int s = it * 16 + l;
            if (s < NSITE_) {
                int r = s / PXT_;
                int lpx = s - r * PXT_;
                float xv = xr[it];
                // closed-form uniform cubic B-spline, knots t_j = 0.4j-2.2
                float ua = (xv + 2.2f) * 2.5f;
                float mf = floorf(ua);
                float u = ua - mf;
                bool ok = (ua >= 0.0f) && (ua < 11.0f);
                float u2 = u * u, u3 = u2 * u;
                const float c6 = 1.0f / 6.0f;
                float Bm  = u3 * c6;
                float Bm1 = (-3.f * u3 + 3.f * u2 + 3.f * u + 1.f) * c6;
                float Bm2 = (3.f * u3 - 6.f * u2 + 4.f) * c6;
                float om = 1.f - u;
                float Bm3 = om * om * om * c6;
                // window placement: shorts (m-2..m+1) = [Bm3,Bm2,Bm1,Bm];
                // short 0 overwritten by silu; shorts >=10 dropped (q<5);
                // short 9 is the zero-weight pad.
                unsigned P0 = pack2(Bm3, Bm2);
                unsigned P1 = pack2(Bm1, Bm);
                int sh = ok ? ((int)mf - 2) : 99;
                int a = sh >> 1;
                bool odd = sh & 1;
                unsigned Q0 = odd ? (P0 << 16) : P0;
                unsigned Q1 = odd ? ((P0 >> 16) | (P1 << 16)) : P1;
                unsigned Q2 = odd ? (P1 >> 16) : 0u;
                unsigned wq[5];
#pragma unroll
                for (int q = 0; q < 5; ++q)
                    wq[q] = (q == a) ? Q0 : (q == a + 1) ? Q1 : (q == a + 2) ? Q2 : 0u;
                float sil = xv * __builtin_amdgcn_rcpf(1.f + __expf(-xv));
                wq[0] = (wq[0] & 0xFFFF0000u) | (unsigned)f2bf(sil);
                unsigned* dst = (unsigned*)(lA + r * LROWT_ + lpx * LPIX_ + ci * 20);
#pragma unroll
                for (int q = 0; q < 5; ++q) dst[q] = wq[q];
            }
        }
    }

    int lane = tid & 63, wv = tid >> 6;
    int lrow = lane & 15, khalf = lane >> 4;
    int p = wv & 1;    // row pair within the 4-row group
    int nt = wv >> 1;  // out-channel half

    // B fragments double-buffered; tap-0 slab prefetched before the barrier
    // so its L2 latency hides under the barrier wait.
    short8 B[2][5];
#pragma unroll
    for (int c = 0; c < 5; ++c)
        B[0][c] = *(const short8*)(wpk + ((size_t)((nt * 5 + c)) * 64 + lane) * 8);

    __syncthreads();

    // ---- Phase 2: wave owns rows (h0+2p, h0+2p+1) x 16 px x 16 ch ----
    f32x4 acc[2] = {{0.f, 0.f, 0.f, 0.f}, {0.f, 0.f, 0.f, 0.f}};

#pragma unroll
    for (int tap = 0; tap < 9; ++tap) {
        int cur = tap & 1, nxt = cur ^ 1;
        if (tap < 8) {
#pragma unroll
            for (int c = 0; c < 5; ++c)
                B[nxt][c] = *(const short8*)(wpk +
                    ((size_t)((((tap + 1) * 2 + nt) * 5 + c)) * 64 + lane) * 8);
        }
        int ki = tap / 3, kj = tap - ki * 3;
        const char* abase = lA + (2 * p + ki) * LROWT_ + (lrow + kj) * LPIX_ + khalf * 16;
        __builtin_amdgcn_s_setprio(1);
#pragma unroll
        for (int c = 0; c < 5; ++c) {
            short8 a0 = *(const short8*)(abase + c * 64);
            short8 a1 = *(const short8*)(abase + LROWT_ + c * 64);
            acc[0] = __builtin_amdgcn_mfma_f32_16x16x32_bf16(a0, B[cur][c], acc[0], 0, 0, 0);
            acc[1] = __builtin_amdgcn_mfma_f32_16x16x32_bf16(a1, B[cur][c], acc[1], 0, 0, 0);
        }
        __builtin_amdgcn_s_setprio(0);
    }

    // ---- Epilogue: C layout (16x16): ch = nt*16 + (lane&15), px = khalf*4+reg.
    // Lanes {g,g+16,g+32,g+48} cover one 64B line per channel.
    int och = nt * 16 + lrow;
    float* ob = out + (size_t)bb * COUT_ * (H_ * W_) + (size_t)och * (H_ * W_) + w0 +
                khalf * 4;
#pragma unroll
    for (int mi = 0; mi < 2; ++mi) {
        int hh = h0 + 2 * p + mi;
        __builtin_nontemporal_store(acc[mi], (f32x4*)(ob + (size_t)hh * W_));
    }
}

// Fallback (only if workspace is too small): direct fp32 compute, slow but correct.
__device__ __forceinline__ void kan_feat_ref(float xv, float* f) {
    float ua = (xv + 2.2f) * 2.5f;
    float mf = floorf(ua);
    int m = (int)mf;
    float u = ua - mf;
    bool ok = (ua >= 0.0f) && (ua < 11.0f);
    float u2 = u * u, u3 = u2 * u;
    const float c6 = 1.0f / 6.0f;
    float Bm  = u3 * c6;
    float Bm1 = (-3.f * u3 + 3.f * u2 + 3.f * u + 1.f) * c6;
    float Bm2 = (3.f * u3 - 6.f * u2 + 4.f) * c6;
    float om = 1.f - u;
    float Bm3 = om * om * om * c6;
    if (!ok) { Bm = 0.f; Bm1 = 0.f; Bm2 = 0.f; Bm3 = 0.f; }
    f[0] = xv / (1.f + __expf(-xv));
#pragma unroll
    for (int j = 0; j < 8; ++j) {
        float v = 0.f;
        v = (m == j)     ? Bm  : v;
        v = (m == j + 1) ? Bm1 : v;
        v = (m == j + 2) ? Bm2 : v;
        v = (m == j + 3) ? Bm3 : v;
        f[1 + j] = v;
    }
}

__global__ void kan_direct(const float* __restrict__ x, const float* __restrict__ bw,
                           const float* __restrict__ sw, const float* __restrict__ sc,
                           float* __restrict__ out) {
    int idx = blockIdx.x * 256 + threadIdx.x;
    if (idx >= NBATCH_ * COUT_ * H_ * W_) return;
    int w = idx & 63, hh = (idx >> 6) & 63, o = (idx >> 12) & 31, b = idx >> 17;
    float acc = 0.0f;
    for (int i = 0; i < CIN_; ++i)
        for (int ki = 0; ki < 3; ++ki)
            for (int kj = 0; kj < 3; ++kj) {
                int hy = hh + ki - 1, wx = w + kj - 1;
                float xv = (hy >= 0 && hy < H_ && wx >= 0 && wx < W_)
                               ? x[(((size_t)b * CIN_ + i) * H_ + hy) * W_ + wx]
                               : 0.0f;
                float f[9];
                kan_feat_ref(xv, f);
                int idx9 = (o * CIN_ + i) * 9 + ki * 3 + kj;
                float a = f[0] * bw[idx9];
                float s = sc[idx9];
#pragma unroll
                for (int cc = 0; cc < 8; ++cc) a += f[1 + cc] * sw[idx9 * 8 + cc] * s;
                acc += a;
            }
    out[idx] = acc;
}

extern "C" void kernel_launch(void* const* d_in, const int* in_sizes, int n_in,
                              void* d_out, int out_size, void* d_ws, size_t ws_size,
                              hipStream_t stream) {
    const float* x  = (const float*)d_in[0];
    const float* bw = (const float*)d_in[1];
    const float* sw = (const float*)d_in[2];
    const float* sc = (const float*)d_in[3];
    float* out = (float*)d_out;

    size_t need = (size_t)9 * 2 * 5 * 64 * 8 * 2;   // 92,160 B packed weights
    if (ws_size >= need) {
        unsigned short* wpk = (unsigned short*)d_ws;
        kan_packw<<<dim3(18), 256, 0, stream>>>(bw, sw, sc, wpk);
        kan_fused<<<dim3(NBATCH_ * 64), 256, 0, stream>>>(x, wpk, out);
    } else {
        kan_direct<<<dim3((NBATCH_ * COUT_ * H_ * W_ + 255) / 256), 256, 0, stream>>>(
            x, bw, sw, sc, out);
    }
}